// Round 5
// baseline (639.662 us; speedup 1.0000x reference)
//
#include <hip/hip_runtime.h>
#include <hip/hip_bf16.h>

// Problem constants (B=2, C=32, T=8, H=32, W=32, V=8192)
#define NQ    16384      // B*T*H*W
#define CDIM  32
#define VSZ   8192
#define PLANE 8192       // T*H*W
#define BSTR  262144     // C*PLANE
#define NEL   524288     // B*C*T*H*W
#define DELTA 0.05f      // rescore margin; >> ~5e-3 worst-case 2*approx-error

typedef unsigned long long u64;
typedef __attribute__((ext_vector_type(8))) short bf16x8;   // 8 bf16 = 4 VGPRs
typedef __attribute__((ext_vector_type(4))) float f32x4;

static __device__ __forceinline__ unsigned short f2bf(float x) {
    unsigned u = __float_as_uint(x);
    return (unsigned short)((u + 0x7FFFu + ((u >> 16) & 1u)) >> 16);   // RNE
}
static __device__ __forceinline__ float bf2f(unsigned short h) {
    return __uint_as_float(((unsigned)h) << 16);
}
// monotone fp32 -> u32 (atomicMin over possibly-negative distances)
static __device__ __forceinline__ unsigned fmap(float f) {
    unsigned u = __float_as_uint(f);
    return (u & 0x80000000u) ? ~u : (u | 0x80000000u);
}
static __device__ __forceinline__ float funmap(unsigned u) {
    return __uint_as_float((u & 0x80000000u) ? (u ^ 0x80000000u) : ~u);
}

// Per-lane query A-fragment: row m, channels quad*8..+7, value -2*f, split hi/lo.
// IDENTICAL code in k_min and k_sel -> bitwise-identical fragments.
static __device__ __forceinline__ void qfrag(const float* __restrict__ f, int m, int quad,
                                             bf16x8& hi, bf16x8& lo) {
    int b = m >> 13, p = m & (PLANE - 1);
    const float* fq = f + b * BSTR + p + quad * 8 * PLANE;
#pragma unroll
    for (int j = 0; j < 8; ++j) {
        float s = -2.0f * fq[j * PLANE];
        unsigned short h = f2bf(s);
        hi[j] = (short)h;
        lo[j] = (short)f2bf(s - bf2f(h));
    }
}

// Stage one 256-row codebook chunk into LDS as [hi 64B][lo 64B], row stride 144 B.
// IDENTICAL code in k_min and k_sel.
static __device__ __forceinline__ void stage_chunk(const float* __restrict__ emb,
                                                   const float* __restrict__ enorm,
                                                   int n0, int tid,
                                                   float* lds_e, float* lds_en) {
#pragma unroll
    for (int i = 0; i < 4; ++i) {
        int g = tid + 256 * i;          // 0..1023
        int row = g >> 2, quad = g & 3; // 8 channels per granule
        const float* src = emb + (n0 + row) * CDIM + quad * 8;
        float4 v0 = *(const float4*)src;
        float4 v1 = *(const float4*)(src + 4);
        float va[8] = {v0.x, v0.y, v0.z, v0.w, v1.x, v1.y, v1.z, v1.w};
        uint4 hv, lv;
        unsigned hw[4], lw[4];
#pragma unroll
        for (int k = 0; k < 4; ++k) {
            unsigned short h0 = f2bf(va[2 * k]), h1 = f2bf(va[2 * k + 1]);
            unsigned short l0 = f2bf(va[2 * k] - bf2f(h0));
            unsigned short l1 = f2bf(va[2 * k + 1] - bf2f(h1));
            hw[k] = (unsigned)h0 | ((unsigned)h1 << 16);
            lw[k] = (unsigned)l0 | ((unsigned)l1 << 16);
        }
        hv.x = hw[0]; hv.y = hw[1]; hv.z = hw[2]; hv.w = hw[3];
        lv.x = lw[0]; lv.y = lw[1]; lv.z = lw[2]; lv.w = lw[3];
        *(uint4*)&lds_e[row * 36 + quad * 4] = hv;        // 144B-stride rows, 16B aligned
        *(uint4*)&lds_e[row * 36 + 16 + quad * 4] = lv;
    }
    lds_en[tid] = enorm[n0 + tid];
}

// ---------------- K_pre: enorm + inits ----------------
__global__ void k_pre(const float* __restrict__ emb, float* __restrict__ enorm,
                      unsigned* __restrict__ qmin, u64* __restrict__ wkeys,
                      int* __restrict__ counts, float* __restrict__ loss_sum) {
    int n = blockIdx.x * 256 + threadIdx.x;   // 0..16383
    qmin[n] = 0xFFFFFFFFu;
    wkeys[n] = ~0ull;
    if (n < VSZ) {
        const float4* row = (const float4*)(emb + n * CDIM);
        float s = 0.f;
#pragma unroll
        for (int r = 0; r < 8; ++r) {
            float4 v = row[r];
            s += v.x * v.x + v.y * v.y + v.z * v.z + v.w * v.w;
        }
        enorm[n] = s;
        counts[n] = 0;
    }
    if (n == 0) *loss_sum = 0.f;
}

// Tile config for k_min/k_sel: grid 1024 = 64 q-blocks x 16 v-halves.
// Block = 4 waves x 64 queries = 256 q; v-range 512 codes in 2 chunks of 256.

// ---------------- K_min: approx min distance per query ----------------
__global__ __launch_bounds__(256, 4) void k_min(
    const float* __restrict__ f, const float* __restrict__ emb,
    const float* __restrict__ enorm, unsigned* __restrict__ qmin) {
    __shared__ __align__(16) float lds_e[256 * 36];   // 36864 B
    __shared__ float lds_en[256];

    const int tid = threadIdx.x;
    const int lane = tid & 63;
    const int wave = tid >> 6;
    const int quad = lane >> 4;
    const int l15 = lane & 15;
    const int qb = blockIdx.x & 63;
    const int vh = blockIdx.x >> 6;
    const int m0 = qb * 256 + wave * 64;

    bf16x8 ah[4], al[4];
#pragma unroll
    for (int sub = 0; sub < 4; ++sub)
        qfrag(f, m0 + sub * 16 + l15, quad, ah[sub], al[sub]);

    float minv[16];
#pragma unroll
    for (int k = 0; k < 16; ++k) minv[k] = 1e30f;

    for (int chunk = 0; chunk < 2; ++chunk) {
        int n0 = vh * 512 + chunk * 256;
        __syncthreads();
        stage_chunk(emb, enorm, n0, tid, lds_e, lds_en);
        __syncthreads();

#pragma unroll 4
        for (int t = 0; t < 16; ++t) {
            int nb = t * 16 + l15;
            const float* er = &lds_e[nb * 36];
            bf16x8 ehf = *(const bf16x8*)(er + quad * 4);
            bf16x8 elf = *(const bf16x8*)(er + 16 + quad * 4);
            float env = lds_en[nb];
            f32x4 cinit = {env, env, env, env};
#pragma unroll
            for (int sub = 0; sub < 4; ++sub) {
                f32x4 acc = cinit;
                acc = __builtin_amdgcn_mfma_f32_16x16x32_bf16(ah[sub], ehf, acc, 0, 0, 0);
                acc = __builtin_amdgcn_mfma_f32_16x16x32_bf16(ah[sub], elf, acc, 0, 0, 0);
                acc = __builtin_amdgcn_mfma_f32_16x16x32_bf16(al[sub], ehf, acc, 0, 0, 0);
                minv[sub * 4 + 0] = fminf(minv[sub * 4 + 0], acc[0]);
                minv[sub * 4 + 1] = fminf(minv[sub * 4 + 1], acc[1]);
                minv[sub * 4 + 2] = fminf(minv[sub * 4 + 2], acc[2]);
                minv[sub * 4 + 3] = fminf(minv[sub * 4 + 3], acc[3]);
            }
        }
    }

    // reduce over the 16 n-lanes (lane bits 0..3); quad preserved
#pragma unroll
    for (int off = 1; off <= 8; off <<= 1) {
#pragma unroll
        for (int k = 0; k < 16; ++k) {
            float o = __shfl_xor(minv[k], off, 64);
            minv[k] = fminf(minv[k], o);
        }
    }
    if (l15 == 0) {
#pragma unroll
        for (int k = 0; k < 16; ++k) {
            int m = m0 + (k >> 2) * 16 + quad * 4 + (k & 3);
            atomicMin(&qmin[m], fmap(minv[k]));
        }
    }
}

// ---------------- K_sel: recompute approx, flag within DELTA, exact fp32 rescore ----------------
__global__ __launch_bounds__(256, 2) void k_sel(
    const float* __restrict__ f, const float* __restrict__ emb,
    const float* __restrict__ enorm, const unsigned* __restrict__ qmin,
    u64* __restrict__ wkeys) {
    __shared__ __align__(16) float lds_e[256 * 36];
    __shared__ float lds_en[256];

    const int tid = threadIdx.x;
    const int lane = tid & 63;
    const int wave = tid >> 6;
    const int quad = lane >> 4;
    const int l15 = lane & 15;
    const int qb = blockIdx.x & 63;
    const int vh = blockIdx.x >> 6;
    const int m0 = qb * 256 + wave * 64;

    bf16x8 ah[4], al[4];
#pragma unroll
    for (int sub = 0; sub < 4; ++sub)
        qfrag(f, m0 + sub * 16 + l15, quad, ah[sub], al[sub]);

    float thr[16];
#pragma unroll
    for (int k = 0; k < 16; ++k) {
        int m = m0 + (k >> 2) * 16 + quad * 4 + (k & 3);
        thr[k] = funmap(qmin[m]) + DELTA;
    }

    for (int chunk = 0; chunk < 2; ++chunk) {
        int n0 = vh * 512 + chunk * 256;
        __syncthreads();
        stage_chunk(emb, enorm, n0, tid, lds_e, lds_en);
        __syncthreads();

#pragma unroll 2
        for (int t = 0; t < 16; ++t) {
            int nb = t * 16 + l15;
            const float* er = &lds_e[nb * 36];
            bf16x8 ehf = *(const bf16x8*)(er + quad * 4);
            bf16x8 elf = *(const bf16x8*)(er + 16 + quad * 4);
            float env = lds_en[nb];
            f32x4 cinit = {env, env, env, env};
            f32x4 accs[4];
            bool hit = false;
#pragma unroll
            for (int sub = 0; sub < 4; ++sub) {
                f32x4 acc = cinit;
                acc = __builtin_amdgcn_mfma_f32_16x16x32_bf16(ah[sub], ehf, acc, 0, 0, 0);
                acc = __builtin_amdgcn_mfma_f32_16x16x32_bf16(ah[sub], elf, acc, 0, 0, 0);
                acc = __builtin_amdgcn_mfma_f32_16x16x32_bf16(al[sub], ehf, acc, 0, 0, 0);
                accs[sub] = acc;
                // EXACT per-row vote (round-4 bug: min-vs-min filter was not conservative)
                hit = hit || (acc[0] < thr[sub * 4 + 0]) || (acc[1] < thr[sub * 4 + 1]) ||
                             (acc[2] < thr[sub * 4 + 2]) || (acc[3] < thr[sub * 4 + 3]);
            }
            if (__any(hit)) {
                int nn = n0 + nb;
                const float* erow = emb + nn * CDIM;
#pragma unroll
                for (int sub = 0; sub < 4; ++sub) {
#pragma unroll
                    for (int r = 0; r < 4; ++r) {
                        if (accs[sub][r] < thr[sub * 4 + r]) {
                            int mm = m0 + sub * 16 + quad * 4 + r;
                            int bq = mm >> 13, pq = mm & (PLANE - 1);
                            const float* fq = f + bq * BSTR + pq;
                            float d = env;
                            for (int c = 0; c < CDIM; ++c) {
                                float qc = -2.0f * fq[c * PLANE];
                                d = fmaf(qc, erow[c], d);   // identical arithmetic to round-2 kernel
                            }
                            u64 key = ((u64)fmap(d) << 32) | (unsigned)nn;
                            atomicMin(&wkeys[mm], key);
                        }
                    }
                }
            }
        }
    }
}

// ---------------- K_gather: emb[idx] -> fh layout, counts ----------------
__global__ void k_gather(const u64* __restrict__ wkeys, const float* __restrict__ emb,
                         float* __restrict__ fh, int* __restrict__ counts) {
    int n = blockIdx.x * 256 + threadIdx.x;   // 16384
    int id = (int)(unsigned)(wkeys[n] & 0xFFFFFFFFull);
    id &= (VSZ - 1);   // safety clamp: logic bug -> absmax error, not memfault
    atomicAdd(&counts[id], 1);
    int b = n >> 13, p = n & (PLANE - 1);
    const float4* row = (const float4*)(emb + id * CDIM);
    float* dst = fh + b * BSTR + p;
#pragma unroll
    for (int r = 0; r < 8; ++r) {
        float4 v = row[r];
        dst[(r * 4 + 0) * PLANE] = v.x;
        dst[(r * 4 + 1) * PLANE] = v.y;
        dst[(r * 4 + 2) * PLANE] = v.z;
        dst[(r * 4 + 3) * PLANE] = v.w;
    }
}

// ---------------- K_conv: fused conv3x3x3 + blend + fhat store + loss ----------------
__global__ __launch_bounds__(256) void k_conv(const float* __restrict__ fh,
                                              const float* __restrict__ cw,
                                              const float* __restrict__ bias,
                                              const float* __restrict__ f,
                                              float* __restrict__ out,
                                              float* __restrict__ loss_sum) {
    const int tid = threadIdx.x;
    const int n = (blockIdx.x & 63) * 256 + tid;   // 0..16383
    const int cog = blockIdx.x >> 6;               // 0..7
    const int b = n >> 13, p = n & (PLANE - 1);
    const int t = p >> 10, h = (p >> 5) & 31, wi = p & 31;

    float msk[27];
#pragma unroll
    for (int dt = 0; dt < 3; ++dt)
#pragma unroll
        for (int dh = 0; dh < 3; ++dh)
#pragma unroll
            for (int dw = 0; dw < 3; ++dw) {
                bool ok = ((unsigned)(t + dt - 1) < 8u) &&
                          ((unsigned)(h + dh - 1) < 32u) &&
                          ((unsigned)(wi + dw - 1) < 32u);
                msk[dt * 9 + dh * 3 + dw] = ok ? 1.0f : 0.0f;
            }

    const float* xb = fh + b * BSTR + p;
    const float* wp = cw + cog * 4 * 864;
    float acc[4] = {0.f, 0.f, 0.f, 0.f};

    for (int ci = 0; ci < CDIM; ++ci) {
        const float* xr = xb + ci * PLANE;
        const float* x0 = xr - 1024;
        const float* x1 = xr;
        const float* x2 = xr + 1024;
#pragma unroll
        for (int dt = 0; dt < 3; ++dt) {
            const float* xp = (dt == 0) ? x0 : ((dt == 1) ? x1 : x2);
#pragma unroll
            for (int dh = 0; dh < 3; ++dh) {
#pragma unroll
                for (int dw = 0; dw < 3; ++dw) {
                    int u = dt * 9 + dh * 3 + dw;
                    float x = xp[(dh - 1) * 32 + (dw - 1)] * msk[u];
#pragma unroll
                    for (int k = 0; k < 4; ++k)
                        acc[k] = fmaf(wp[k * 864 + ci * 27 + u], x, acc[k]);
                }
            }
        }
    }

    float s = 0.f;
#pragma unroll
    for (int k = 0; k < 4; ++k) {
        int co = cog * 4 + k;
        long off = (long)b * BSTR + (long)co * PLANE + p;
        float fhc = fh[off];
        float fv = f[off];
        float o = 0.5f * fhc + 0.5f * (acc[k] + bias[co]);
        out[off] = o;
        float d = o - fv;
        s = fmaf(d, d, s);
    }
#pragma unroll
    for (int off = 32; off > 0; off >>= 1) s += __shfl_down(s, off, 64);
    __shared__ float ls[4];
    if ((tid & 63) == 0) ls[tid >> 6] = s;
    __syncthreads();
    if (tid == 0) atomicAdd(loss_sum, ls[0] + ls[1] + ls[2] + ls[3]);
}

// ---------------- K_scalars ----------------
__global__ void k_scalars(const int* __restrict__ counts,
                          const float* __restrict__ loss_sum, float* __restrict__ out) {
    int tid = threadIdx.x;
    int used = 0;
#pragma unroll
    for (int r = 0; r < 32; ++r) used += (counts[tid + 256 * r] > 0) ? 1 : 0;
#pragma unroll
    for (int off = 32; off > 0; off >>= 1) used += __shfl_down(used, off, 64);
    __shared__ int us[4];
    if ((tid & 63) == 0) us[tid >> 6] = used;
    __syncthreads();
    if (tid == 0) {
        int u = us[0] + us[1] + us[2] + us[3];
        out[NEL + 0] = 1.25f * (*loss_sum) / (float)NEL;
        out[NEL + 1] = ((float)u / (float)VSZ) * 100.0f;
    }
}

extern "C" void kernel_launch(void* const* d_in, const int* in_sizes, int n_in,
                              void* d_out, int out_size, void* d_ws, size_t ws_size,
                              hipStream_t stream) {
    const float* f      = (const float*)d_in[0];
    const float* emb    = (const float*)d_in[1];
    const float* conv_w = (const float*)d_in[2];
    const float* conv_b = (const float*)d_in[3];
    float* out = (float*)d_out;
    float* ws = (float*)d_ws;

    // ws layout (float offsets) — total ~2.37 MB (round-2 proven envelope)
    float*    enorm    = ws;                        // [0, 8192)
    unsigned* qmin     = (unsigned*)(ws + 8192);    // [8192, 24576)  u32 x 16384
    u64*      wkeys    = (u64*)(ws + 24576);        // [24576, 57344) u64 x 16384
    int*      counts   = (int*)(ws + 57344);        // [57344, 65536)
    float*    loss_sum = ws + 65536;                // 1 (+pad/guard to 67648)
    float*    fh       = ws + 67648;                // 524288 + right margin

    k_pre<<<64, 256, 0, stream>>>(emb, enorm, qmin, wkeys, counts, loss_sum);
    k_min<<<1024, 256, 0, stream>>>(f, emb, enorm, qmin);
    k_sel<<<1024, 256, 0, stream>>>(f, emb, enorm, qmin, wkeys);
    k_gather<<<64, 256, 0, stream>>>(wkeys, emb, fh, counts);
    k_conv<<<512, 256, 0, stream>>>(fh, conv_w, conv_b, f, out, loss_sum);
    k_scalars<<<1, 256, 0, stream>>>(counts, loss_sum, out);
}

// Round 6
// 354.375 us; speedup vs baseline: 1.8050x; 1.8050x over previous
//
#include <hip/hip_runtime.h>
#include <hip/hip_bf16.h>

// Problem constants (B=2, C=32, T=8, H=32, W=32, V=8192)
#define NQ    16384      // B*T*H*W
#define CDIM  32
#define VSZ   8192
#define PLANE 8192       // T*H*W
#define BSTR  262144     // C*PLANE
#define NEL   524288     // B*C*T*H*W
#define DELTA 0.05f      // rescore margin; >> ~2e-3 worst-case 2*approx-error
#define QCAP  262144     // candidate queue capacity (1 MB, overlaid on fh region)

typedef unsigned long long u64;
typedef __attribute__((ext_vector_type(8))) short bf16x8;   // 8 bf16 = 4 VGPRs
typedef __attribute__((ext_vector_type(4))) float f32x4;

static __device__ __forceinline__ unsigned short f2bf(float x) {
    unsigned u = __float_as_uint(x);
    return (unsigned short)((u + 0x7FFFu + ((u >> 16) & 1u)) >> 16);   // RNE
}
static __device__ __forceinline__ float bf2f(unsigned short h) {
    return __uint_as_float(((unsigned)h) << 16);
}
// monotone fp32 -> u32 (atomicMin over possibly-negative distances)
static __device__ __forceinline__ unsigned fmap(float f) {
    unsigned u = __float_as_uint(f);
    return (u & 0x80000000u) ? ~u : (u | 0x80000000u);
}
static __device__ __forceinline__ float funmap(unsigned u) {
    return __uint_as_float((u & 0x80000000u) ? (u ^ 0x80000000u) : ~u);
}

// Per-lane query A-fragment: row m, channels quad*8..+7, value -2*f, split hi/lo.
// IDENTICAL in k_min and k_sel -> bitwise-identical fragments.
static __device__ __forceinline__ void qfrag(const float* __restrict__ f, int m, int quad,
                                             bf16x8& hi, bf16x8& lo) {
    int b = m >> 13, p = m & (PLANE - 1);
    const float* fq = f + b * BSTR + p + quad * 8 * PLANE;
#pragma unroll
    for (int j = 0; j < 8; ++j) {
        float s = -2.0f * fq[j * PLANE];
        unsigned short h = f2bf(s);
        hi[j] = (short)h;
        lo[j] = (short)f2bf(s - bf2f(h));
    }
}

// Stage one 256-row codebook chunk into LDS as [hi 64B][lo 64B], row stride 144 B.
// IDENTICAL in k_min and k_sel.
static __device__ __forceinline__ void stage_chunk(const float* __restrict__ emb,
                                                   const float* __restrict__ enorm,
                                                   int n0, int tid,
                                                   float* lds_e, float* lds_en) {
#pragma unroll
    for (int i = 0; i < 4; ++i) {
        int g = tid + 256 * i;          // 0..1023
        int row = g >> 2, quad = g & 3; // 8 channels per granule
        const float* src = emb + (n0 + row) * CDIM + quad * 8;
        float4 v0 = *(const float4*)src;
        float4 v1 = *(const float4*)(src + 4);
        float va[8] = {v0.x, v0.y, v0.z, v0.w, v1.x, v1.y, v1.z, v1.w};
        uint4 hv, lv;
        unsigned hw[4], lw[4];
#pragma unroll
        for (int k = 0; k < 4; ++k) {
            unsigned short h0 = f2bf(va[2 * k]), h1 = f2bf(va[2 * k + 1]);
            unsigned short l0 = f2bf(va[2 * k] - bf2f(h0));
            unsigned short l1 = f2bf(va[2 * k + 1] - bf2f(h1));
            hw[k] = (unsigned)h0 | ((unsigned)h1 << 16);
            lw[k] = (unsigned)l0 | ((unsigned)l1 << 16);
        }
        hv.x = hw[0]; hv.y = hw[1]; hv.z = hw[2]; hv.w = hw[3];
        lv.x = lw[0]; lv.y = lw[1]; lv.z = lw[2]; lv.w = lw[3];
        *(uint4*)&lds_e[row * 36 + quad * 4] = hv;        // 144B-stride rows, 16B aligned
        *(uint4*)&lds_e[row * 36 + 16 + quad * 4] = lv;
    }
    lds_en[tid] = enorm[n0 + tid];
}

// ---------------- K_pre: enorm + inits ----------------
__global__ void k_pre(const float* __restrict__ emb, float* __restrict__ enorm,
                      unsigned* __restrict__ qmin, u64* __restrict__ wkeys,
                      int* __restrict__ counts, float* __restrict__ loss_sum,
                      int* __restrict__ qcnt) {
    int n = blockIdx.x * 256 + threadIdx.x;   // 0..16383
    qmin[n] = 0xFFFFFFFFu;
    wkeys[n] = ~0ull;
    if (n < VSZ) {
        const float4* row = (const float4*)(emb + n * CDIM);
        float s = 0.f;
#pragma unroll
        for (int r = 0; r < 8; ++r) {
            float4 v = row[r];
            s += v.x * v.x + v.y * v.y + v.z * v.z + v.w * v.w;
        }
        enorm[n] = s;
        counts[n] = 0;
    }
    if (n == 0) { *loss_sum = 0.f; *qcnt = 0; }
}

// Tile config for k_min/k_sel: grid 1024 = 64 q-blocks x 16 v-halves.
// Block = 4 waves x 64 queries = 256 q; v-range 512 codes in 2 chunks of 256.

// ---------------- K_min: approx min distance per query ----------------
__global__ __launch_bounds__(256, 4) void k_min(
    const float* __restrict__ f, const float* __restrict__ emb,
    const float* __restrict__ enorm, unsigned* __restrict__ qmin) {
    __shared__ __align__(16) float lds_e[256 * 36];   // 36864 B
    __shared__ float lds_en[256];

    const int tid = threadIdx.x;
    const int lane = tid & 63;
    const int wave = tid >> 6;
    const int quad = lane >> 4;
    const int l15 = lane & 15;
    const int qb = blockIdx.x & 63;
    const int vh = blockIdx.x >> 6;
    const int m0 = qb * 256 + wave * 64;

    bf16x8 ah[4], al[4];
#pragma unroll
    for (int sub = 0; sub < 4; ++sub)
        qfrag(f, m0 + sub * 16 + l15, quad, ah[sub], al[sub]);

    float minv[16];
#pragma unroll
    for (int k = 0; k < 16; ++k) minv[k] = 1e30f;

    for (int chunk = 0; chunk < 2; ++chunk) {
        int n0 = vh * 512 + chunk * 256;
        __syncthreads();
        stage_chunk(emb, enorm, n0, tid, lds_e, lds_en);
        __syncthreads();

#pragma unroll 4
        for (int t = 0; t < 16; ++t) {
            int nb = t * 16 + l15;
            const float* er = &lds_e[nb * 36];
            bf16x8 ehf = *(const bf16x8*)(er + quad * 4);
            bf16x8 elf = *(const bf16x8*)(er + 16 + quad * 4);
            float env = lds_en[nb];
            f32x4 cinit = {env, env, env, env};
#pragma unroll
            for (int sub = 0; sub < 4; ++sub) {
                f32x4 acc = cinit;
                acc = __builtin_amdgcn_mfma_f32_16x16x32_bf16(ah[sub], ehf, acc, 0, 0, 0);
                acc = __builtin_amdgcn_mfma_f32_16x16x32_bf16(ah[sub], elf, acc, 0, 0, 0);
                acc = __builtin_amdgcn_mfma_f32_16x16x32_bf16(al[sub], ehf, acc, 0, 0, 0);
                minv[sub * 4 + 0] = fminf(minv[sub * 4 + 0], acc[0]);
                minv[sub * 4 + 1] = fminf(minv[sub * 4 + 1], acc[1]);
                minv[sub * 4 + 2] = fminf(minv[sub * 4 + 2], acc[2]);
                minv[sub * 4 + 3] = fminf(minv[sub * 4 + 3], acc[3]);
            }
        }
    }

    // reduce over the 16 n-lanes (lane bits 0..3); quad preserved
#pragma unroll
    for (int off = 1; off <= 8; off <<= 1) {
#pragma unroll
        for (int k = 0; k < 16; ++k) {
            float o = __shfl_xor(minv[k], off, 64);
            minv[k] = fminf(minv[k], o);
        }
    }
    if (l15 == 0) {
#pragma unroll
        for (int k = 0; k < 16; ++k) {
            int m = m0 + (k >> 2) * 16 + quad * 4 + (k & 3);
            atomicMin(&qmin[m], fmap(minv[k]));
        }
    }
}

// ---------------- K_sel: recompute approx, enqueue candidates within DELTA ----------------
// Register-lean hot loop: thr in LDS, acc processed immediately, NO rescore body here.
__global__ __launch_bounds__(256, 4) void k_sel(
    const float* __restrict__ f, const float* __restrict__ emb,
    const float* __restrict__ enorm, const unsigned* __restrict__ qmin,
    unsigned* __restrict__ queue, int* __restrict__ qcnt) {
    __shared__ __align__(16) float lds_e[256 * 36];
    __shared__ float lds_en[256];
    __shared__ __align__(16) float lds_thr[256];

    const int tid = threadIdx.x;
    const int lane = tid & 63;
    const int wave = tid >> 6;
    const int quad = lane >> 4;
    const int l15 = lane & 15;
    const int qb = blockIdx.x & 63;
    const int vh = blockIdx.x >> 6;
    const int m0 = qb * 256 + wave * 64;

    bf16x8 ah[4], al[4];
#pragma unroll
    for (int sub = 0; sub < 4; ++sub)
        qfrag(f, m0 + sub * 16 + l15, quad, ah[sub], al[sub]);

    // thr_lds[tid] corresponds to query m = qb*256 + tid = m0-of-wave(tid) layout
    lds_thr[tid] = funmap(qmin[qb * 256 + tid]) + DELTA;

    for (int chunk = 0; chunk < 2; ++chunk) {
        int n0 = vh * 512 + chunk * 256;
        __syncthreads();                       // also covers lds_thr on first pass
        stage_chunk(emb, enorm, n0, tid, lds_e, lds_en);
        __syncthreads();

#pragma unroll 2
        for (int t = 0; t < 16; ++t) {
            int nb = t * 16 + l15;
            const float* er = &lds_e[nb * 36];
            bf16x8 ehf = *(const bf16x8*)(er + quad * 4);
            bf16x8 elf = *(const bf16x8*)(er + 16 + quad * 4);
            float env = lds_en[nb];
            f32x4 cinit = {env, env, env, env};
            int nn = n0 + nb;
#pragma unroll
            for (int sub = 0; sub < 4; ++sub) {
                f32x4 acc = cinit;
                acc = __builtin_amdgcn_mfma_f32_16x16x32_bf16(ah[sub], ehf, acc, 0, 0, 0);
                acc = __builtin_amdgcn_mfma_f32_16x16x32_bf16(ah[sub], elf, acc, 0, 0, 0);
                acc = __builtin_amdgcn_mfma_f32_16x16x32_bf16(al[sub], ehf, acc, 0, 0, 0);
                // thr for this lane's 4 rows: queries m0 + sub*16 + quad*4 + r
                f32x4 tv = *(const f32x4*)&lds_thr[wave * 64 + sub * 16 + quad * 4];
#pragma unroll
                for (int r = 0; r < 4; ++r) {
                    if (acc[r] < tv[r]) {      // rare: ~1 per query over full sweep
                        int mm = m0 + sub * 16 + quad * 4 + r;
                        int qi = atomicAdd(qcnt, 1);
                        if (qi < QCAP) queue[qi] = ((unsigned)mm << 13) | (unsigned)nn;
                    }
                }
            }
        }
    }
}

// ---------------- K_fix: exact fp32 rescore of queued candidates ----------------
__global__ void k_fix(const unsigned* __restrict__ queue, const int* __restrict__ qcnt,
                      const float* __restrict__ f, const float* __restrict__ emb,
                      const float* __restrict__ enorm, u64* __restrict__ wkeys) {
    int total = *qcnt;
    if (total > QCAP) total = QCAP;
    for (int i = blockIdx.x * 256 + threadIdx.x; i < total; i += 64 * 256) {
        unsigned e = queue[i];
        int m = (int)(e >> 13);
        int n = (int)(e & (VSZ - 1));
        int b = m >> 13, p = m & (PLANE - 1);
        const float* fq = f + b * BSTR + p;
        const float* erow = emb + n * CDIM;
        float d = enorm[n];
        for (int c = 0; c < CDIM; ++c) {
            float qc = -2.0f * fq[c * PLANE];
            d = fmaf(qc, erow[c], d);          // identical arithmetic to round-2 kernel
        }
        u64 key = ((u64)fmap(d) << 32) | (unsigned)n;
        atomicMin(&wkeys[m], key);
    }
}

// ---------------- K_gather: emb[idx] -> fh layout, counts ----------------
__global__ void k_gather(const u64* __restrict__ wkeys, const float* __restrict__ emb,
                         float* __restrict__ fh, int* __restrict__ counts) {
    int n = blockIdx.x * 256 + threadIdx.x;   // 16384
    int id = (int)(unsigned)(wkeys[n] & 0xFFFFFFFFull);
    id &= (VSZ - 1);   // safety clamp: logic bug -> absmax error, not memfault
    atomicAdd(&counts[id], 1);
    int b = n >> 13, p = n & (PLANE - 1);
    const float4* row = (const float4*)(emb + id * CDIM);
    float* dst = fh + b * BSTR + p;
#pragma unroll
    for (int r = 0; r < 8; ++r) {
        float4 v = row[r];
        dst[(r * 4 + 0) * PLANE] = v.x;
        dst[(r * 4 + 1) * PLANE] = v.y;
        dst[(r * 4 + 2) * PLANE] = v.z;
        dst[(r * 4 + 3) * PLANE] = v.w;
    }
}

// ---------------- K_conv: fused conv3x3x3 + blend + fhat store + loss ----------------
__global__ __launch_bounds__(256) void k_conv(const float* __restrict__ fh,
                                              const float* __restrict__ cw,
                                              const float* __restrict__ bias,
                                              const float* __restrict__ f,
                                              float* __restrict__ out,
                                              float* __restrict__ loss_sum) {
    const int tid = threadIdx.x;
    const int n = (blockIdx.x & 63) * 256 + tid;   // 0..16383
    const int cog = blockIdx.x >> 6;               // 0..7
    const int b = n >> 13, p = n & (PLANE - 1);
    const int t = p >> 10, h = (p >> 5) & 31, wi = p & 31;

    float msk[27];
#pragma unroll
    for (int dt = 0; dt < 3; ++dt)
#pragma unroll
        for (int dh = 0; dh < 3; ++dh)
#pragma unroll
            for (int dw = 0; dw < 3; ++dw) {
                bool ok = ((unsigned)(t + dt - 1) < 8u) &&
                          ((unsigned)(h + dh - 1) < 32u) &&
                          ((unsigned)(wi + dw - 1) < 32u);
                msk[dt * 9 + dh * 3 + dw] = ok ? 1.0f : 0.0f;
            }

    const float* xb = fh + b * BSTR + p;
    const float* wp = cw + cog * 4 * 864;
    float acc[4] = {0.f, 0.f, 0.f, 0.f};

    for (int ci = 0; ci < CDIM; ++ci) {
        const float* xr = xb + ci * PLANE;
        const float* x0 = xr - 1024;
        const float* x1 = xr;
        const float* x2 = xr + 1024;
#pragma unroll
        for (int dt = 0; dt < 3; ++dt) {
            const float* xp = (dt == 0) ? x0 : ((dt == 1) ? x1 : x2);
#pragma unroll
            for (int dh = 0; dh < 3; ++dh) {
#pragma unroll
                for (int dw = 0; dw < 3; ++dw) {
                    int u = dt * 9 + dh * 3 + dw;
                    float x = xp[(dh - 1) * 32 + (dw - 1)] * msk[u];
#pragma unroll
                    for (int k = 0; k < 4; ++k)
                        acc[k] = fmaf(wp[k * 864 + ci * 27 + u], x, acc[k]);
                }
            }
        }
    }

    float s = 0.f;
#pragma unroll
    for (int k = 0; k < 4; ++k) {
        int co = cog * 4 + k;
        long off = (long)b * BSTR + (long)co * PLANE + p;
        float fhc = fh[off];
        float fv = f[off];
        float o = 0.5f * fhc + 0.5f * (acc[k] + bias[co]);
        out[off] = o;
        float d = o - fv;
        s = fmaf(d, d, s);
    }
#pragma unroll
    for (int off = 32; off > 0; off >>= 1) s += __shfl_down(s, off, 64);
    __shared__ float ls[4];
    if ((tid & 63) == 0) ls[tid >> 6] = s;
    __syncthreads();
    if (tid == 0) atomicAdd(loss_sum, ls[0] + ls[1] + ls[2] + ls[3]);
}

// ---------------- K_scalars ----------------
__global__ void k_scalars(const int* __restrict__ counts,
                          const float* __restrict__ loss_sum, float* __restrict__ out) {
    int tid = threadIdx.x;
    int used = 0;
#pragma unroll
    for (int r = 0; r < 32; ++r) used += (counts[tid + 256 * r] > 0) ? 1 : 0;
#pragma unroll
    for (int off = 32; off > 0; off >>= 1) used += __shfl_down(used, off, 64);
    __shared__ int us[4];
    if ((tid & 63) == 0) us[tid >> 6] = used;
    __syncthreads();
    if (tid == 0) {
        int u = us[0] + us[1] + us[2] + us[3];
        out[NEL + 0] = 1.25f * (*loss_sum) / (float)NEL;
        out[NEL + 1] = ((float)u / (float)VSZ) * 100.0f;
    }
}

extern "C" void kernel_launch(void* const* d_in, const int* in_sizes, int n_in,
                              void* d_out, int out_size, void* d_ws, size_t ws_size,
                              hipStream_t stream) {
    const float* f      = (const float*)d_in[0];
    const float* emb    = (const float*)d_in[1];
    const float* conv_w = (const float*)d_in[2];
    const float* conv_b = (const float*)d_in[3];
    float* out = (float*)d_out;
    float* ws = (float*)d_ws;

    // ws layout (float offsets) — total ~2.37 MB (round-5 proven envelope).
    float*    enorm    = ws;                        // [0, 8192)
    unsigned* qmin     = (unsigned*)(ws + 8192);    // [8192, 24576)  u32 x 16384
    u64*      wkeys    = (u64*)(ws + 24576);        // [24576, 57344) u64 x 16384
    int*      counts   = (int*)(ws + 57344);        // [57344, 65536)
    float*    loss_sum = ws + 65536;                // 1
    int*      qcnt     = (int*)(ws + 65552);        // 1 (+pad/guard to 67648)
    float*    fh       = ws + 67648;                // 524288 + right margin
    // queue overlaid on fh region: used by k_sel/k_fix BEFORE k_gather writes fh
    unsigned* queue    = (unsigned*)fh;             // QCAP u32 = 1 MB < fh's 2 MB

    k_pre<<<64, 256, 0, stream>>>(emb, enorm, qmin, wkeys, counts, loss_sum, qcnt);
    k_min<<<1024, 256, 0, stream>>>(f, emb, enorm, qmin);
    k_sel<<<1024, 256, 0, stream>>>(f, emb, enorm, qmin, queue, qcnt);
    k_fix<<<64, 256, 0, stream>>>(queue, qcnt, f, emb, enorm, wkeys);
    k_gather<<<64, 256, 0, stream>>>(wkeys, emb, fh, counts);
    k_conv<<<512, 256, 0, stream>>>(fh, conv_w, conv_b, f, out, loss_sum);
    k_scalars<<<1, 256, 0, stream>>>(counts, loss_sum, out);
}

// Round 7
// 287.645 us; speedup vs baseline: 2.2238x; 1.2320x over previous
//
#include <hip/hip_runtime.h>
#include <hip/hip_bf16.h>

// Problem constants (B=2, C=32, T=8, H=32, W=32, V=8192)
#define NQ    16384      // B*T*H*W
#define CDIM  32
#define VSZ   8192
#define PLANE 8192       // T*H*W
#define BSTR  262144     // C*PLANE
#define NEL   524288     // B*C*T*H*W
// Worst-case |d_approx - d_exact| <= ~0.028 (dropped sl*el + split residuals,
// coherent over 32 ch, + fp32 accum-order diffs). Flag if approx gap <= 2*eps
// with margin:
#define GAP_EPS 0.125f

typedef unsigned long long u64;
typedef __attribute__((ext_vector_type(8))) short bf16x8;   // 8 bf16 = 4 VGPRs
typedef __attribute__((ext_vector_type(4))) float f32x4;

static __device__ __forceinline__ unsigned short f2bf(float x) {
    unsigned u = __float_as_uint(x);
    return (unsigned short)((u + 0x7FFFu + ((u >> 16) & 1u)) >> 16);   // RNE
}
static __device__ __forceinline__ float bf2f(unsigned short h) {
    return __uint_as_float(((unsigned)h) << 16);
}
// monotone fp32 -> u32 (order-preserving, handles negatives)
static __device__ __forceinline__ unsigned fmap(float f) {
    unsigned u = __float_as_uint(f);
    return (u & 0x80000000u) ? ~u : (u | 0x80000000u);
}
static __device__ __forceinline__ float funmap(unsigned u) {
    return __uint_as_float((u & 0x80000000u) ? (u ^ 0x80000000u) : ~u);
}

// Per-lane query A-fragment: row m, channels quad*8..+7, value -2*f, split hi/lo.
static __device__ __forceinline__ void qfrag(const float* __restrict__ f, int m, int quad,
                                             bf16x8& hi, bf16x8& lo) {
    int b = m >> 13, p = m & (PLANE - 1);
    const float* fq = f + b * BSTR + p + quad * 8 * PLANE;
#pragma unroll
    for (int j = 0; j < 8; ++j) {
        float s = -2.0f * fq[j * PLANE];
        unsigned short h = f2bf(s);
        hi[j] = (short)h;
        lo[j] = (short)f2bf(s - bf2f(h));
    }
}

// Stage one 256-row codebook chunk into LDS as [hi 64B][lo 64B], row stride 144 B.
static __device__ __forceinline__ void stage_chunk(const float* __restrict__ emb,
                                                   const float* __restrict__ enorm,
                                                   int n0, int tid,
                                                   float* lds_e, float* lds_en) {
#pragma unroll
    for (int i = 0; i < 4; ++i) {
        int g = tid + 256 * i;          // 0..1023
        int row = g >> 2, quad = g & 3; // 8 channels per granule
        const float* src = emb + (n0 + row) * CDIM + quad * 8;
        float4 v0 = *(const float4*)src;
        float4 v1 = *(const float4*)(src + 4);
        float va[8] = {v0.x, v0.y, v0.z, v0.w, v1.x, v1.y, v1.z, v1.w};
        uint4 hv, lv;
        unsigned hw[4], lw[4];
#pragma unroll
        for (int k = 0; k < 4; ++k) {
            unsigned short h0 = f2bf(va[2 * k]), h1 = f2bf(va[2 * k + 1]);
            unsigned short l0 = f2bf(va[2 * k] - bf2f(h0));
            unsigned short l1 = f2bf(va[2 * k + 1] - bf2f(h1));
            hw[k] = (unsigned)h0 | ((unsigned)h1 << 16);
            lw[k] = (unsigned)l0 | ((unsigned)l1 << 16);
        }
        hv.x = hw[0]; hv.y = hw[1]; hv.z = hw[2]; hv.w = hw[3];
        lv.x = lw[0]; lv.y = lw[1]; lv.z = lw[2]; lv.w = lw[3];
        *(uint4*)&lds_e[row * 36 + quad * 4] = hv;
        *(uint4*)&lds_e[row * 36 + 16 + quad * 4] = lv;
    }
    lds_en[tid] = enorm[n0 + tid];
}

// ---------------- K_pre: enorm + inits ----------------
__global__ void k_pre(const float* __restrict__ emb, float* __restrict__ enorm,
                      int* __restrict__ counts, float* __restrict__ loss_sum,
                      int* __restrict__ rq_cnt) {
    int n = blockIdx.x * 256 + threadIdx.x;   // 0..16383
    if (n < VSZ) {
        const float4* row = (const float4*)(emb + n * CDIM);
        float s = 0.f;
#pragma unroll
        for (int r = 0; r < 8; ++r) {
            float4 v = row[r];
            s += v.x * v.x + v.y * v.y + v.z * v.z + v.w * v.w;
        }
        enorm[n] = s;
        counts[n] = 0;
    }
    if (n == 0) { *loss_sum = 0.f; *rq_cnt = 0; }
}

// ---------------- K_minidx: single sweep, per-(vh,query) (best,idx,sec) ----------------
// grid 1024 = 64 q-blocks x 16 v-halves; block = 4 waves x 64 queries;
// v-range 512 codes in 2 chunks of 256. Branch-free tracking, no atomics.
__global__ __launch_bounds__(256, 4) void k_minidx(
    const float* __restrict__ f, const float* __restrict__ emb,
    const float* __restrict__ enorm,
    u64* __restrict__ part_best, unsigned* __restrict__ part_sec) {
    __shared__ __align__(16) float lds_e[256 * 36];   // 36864 B
    __shared__ float lds_en[256];

    const int tid = threadIdx.x;
    const int lane = tid & 63;
    const int wave = tid >> 6;
    const int quad = lane >> 4;
    const int l15 = lane & 15;
    const int qb = blockIdx.x & 63;
    const int vh = blockIdx.x >> 6;
    const int m0 = qb * 256 + wave * 64;

    bf16x8 ah[4], al[4];
#pragma unroll
    for (int sub = 0; sub < 4; ++sub)
        qfrag(f, m0 + sub * 16 + l15, quad, ah[sub], al[sub]);

    unsigned bval[16], sval[16], bj[16];
#pragma unroll
    for (int k = 0; k < 16; ++k) { bval[k] = 0xFFFFFFFFu; sval[k] = 0xFFFFFFFFu; bj[k] = 0; }

    for (int chunk = 0; chunk < 2; ++chunk) {
        int n0 = vh * 512 + chunk * 256;
        __syncthreads();
        stage_chunk(emb, enorm, n0, tid, lds_e, lds_en);
        __syncthreads();

        // prefetch t=0
        const float* er0 = &lds_e[l15 * 36];
        bf16x8 ehf = *(const bf16x8*)(er0 + quad * 4);
        bf16x8 elf = *(const bf16x8*)(er0 + 16 + quad * 4);
        float env = lds_en[l15];

#pragma unroll 2
        for (int t = 0; t < 16; ++t) {
            bf16x8 nehf, nelf; float nenv = 0.f;
            if (t < 15) {                         // prefetch t+1 (hides ds_read latency)
                const float* ern = &lds_e[((t + 1) * 16 + l15) * 36];
                nehf = *(const bf16x8*)(ern + quad * 4);
                nelf = *(const bf16x8*)(ern + 16 + quad * 4);
                nenv = lds_en[(t + 1) * 16 + l15];
            }
            unsigned j = (unsigned)(chunk * 16 + t);
            f32x4 cinit = {env, env, env, env};
#pragma unroll
            for (int sub = 0; sub < 4; ++sub) {
                f32x4 acc = cinit;
                acc = __builtin_amdgcn_mfma_f32_16x16x32_bf16(ah[sub], ehf, acc, 0, 0, 0);
                acc = __builtin_amdgcn_mfma_f32_16x16x32_bf16(ah[sub], elf, acc, 0, 0, 0);
                acc = __builtin_amdgcn_mfma_f32_16x16x32_bf16(al[sub], ehf, acc, 0, 0, 0);
#pragma unroll
                for (int r = 0; r < 4; ++r) {
                    int k = sub * 4 + r;
                    unsigned af = fmap(acc[r]);
                    bool isb = af < bval[k];
                    unsigned nsv = (af < sval[k]) ? af : sval[k];
                    sval[k] = isb ? bval[k] : nsv;   // new best -> old best becomes sec
                    bval[k] = isb ? af : bval[k];
                    bj[k]   = isb ? j : bj[k];
                }
            }
            ehf = nehf; elf = nelf; env = nenv;
        }
    }

    // Build keys with real code index; butterfly-merge (best,sec) over the 16 n-lanes
    u64 bk[16];
#pragma unroll
    for (int k = 0; k < 16; ++k) {
        unsigned nn = (unsigned)(vh * 512) + (bj[k] >> 4) * 256 + (bj[k] & 15) * 16 + (unsigned)l15;
        bk[k] = ((u64)bval[k] << 32) | nn;
    }
#pragma unroll
    for (int off = 1; off <= 8; off <<= 1) {
#pragma unroll
        for (int k = 0; k < 16; ++k) {
            u64 ob = __shfl_xor(bk[k], off, 64);
            unsigned os = __shfl_xor(sval[k], off, 64);
            u64 lo = (ob < bk[k]) ? ob : bk[k];
            u64 hi = (ob < bk[k]) ? bk[k] : ob;
            unsigned hv = (unsigned)(hi >> 32);
            unsigned s2 = (sval[k] < os) ? sval[k] : os;
            sval[k] = (hv < s2) ? hv : s2;
            bk[k] = lo;
        }
    }
    if (l15 == 0) {
#pragma unroll
        for (int k = 0; k < 16; ++k) {
            int m = m0 + (k >> 2) * 16 + quad * 4 + (k & 3);
            part_best[vh * NQ + m] = bk[k];
            part_sec[vh * NQ + m] = sval[k];
        }
    }
}

// ---------------- K_reduce: fold 16 partials -> wkeys + flag near-ties ----------------
__global__ void k_reduce(const u64* __restrict__ part_best, const unsigned* __restrict__ part_sec,
                         u64* __restrict__ wkeys, unsigned* __restrict__ rq,
                         int* __restrict__ rq_cnt) {
    int m = blockIdx.x * 256 + threadIdx.x;   // 16384
    u64 best = part_best[m];
    int wp = 0;
    unsigned g2 = 0xFFFFFFFFu;
#pragma unroll
    for (int p = 1; p < 16; ++p) {
        u64 b = part_best[p * NQ + m];
        unsigned bv;
        if (b < best) { bv = (unsigned)(best >> 32); best = b; wp = p; }
        else          { bv = (unsigned)(b >> 32); }
        g2 = (bv < g2) ? bv : g2;
    }
    unsigned ws = part_sec[wp * NQ + m];
    g2 = (ws < g2) ? ws : g2;
    wkeys[m] = best;
    float gap = funmap(g2) - funmap((unsigned)(best >> 32));
    if (gap <= GAP_EPS) {
        int i = atomicAdd(rq_cnt, 1);
        rq[i] = (unsigned)m;
    }
}

// ---------------- K_rescan: exact fp32 full scan for flagged queries ----------------
// One wave per flagged query; identical arithmetic to the round-2 passing kernel.
__global__ void k_rescan(const unsigned* __restrict__ rq, const int* __restrict__ rq_cnt,
                         const float* __restrict__ f, const float* __restrict__ emb,
                         const float* __restrict__ enorm, u64* __restrict__ wkeys) {
    int total = *rq_cnt;
    int wid = (blockIdx.x * 256 + threadIdx.x) >> 6;   // 1024 waves
    int lane = threadIdx.x & 63;
    for (int i = wid; i < total; i += 1024) {
        int m = (int)rq[i];
        int b = m >> 13, p = m & (PLANE - 1);
        const float* fq = f + b * BSTR + p;
        float q[CDIM];
#pragma unroll
        for (int c = 0; c < CDIM; ++c) q[c] = -2.0f * fq[c * PLANE];
        u64 key = ~0ull;
        for (int n = lane; n < VSZ; n += 64) {
            const float* er = emb + n * CDIM;
            float d = enorm[n];
#pragma unroll
            for (int c = 0; c < CDIM; ++c) d = fmaf(q[c], er[c], d);
            u64 kk = ((u64)fmap(d) << 32) | (unsigned)n;
            if (kk < key) key = kk;    // strict <: keeps smallest n on exact ties
        }
#pragma unroll
        for (int off = 1; off <= 32; off <<= 1) {
            u64 o = __shfl_xor(key, off, 64);
            if (o < key) key = o;
        }
        if (lane == 0) wkeys[m] = key;
    }
}

// ---------------- K_gather: emb[idx] -> fh layout, counts ----------------
__global__ void k_gather(const u64* __restrict__ wkeys, const float* __restrict__ emb,
                         float* __restrict__ fh, int* __restrict__ counts) {
    int n = blockIdx.x * 256 + threadIdx.x;   // 16384
    int id = (int)(unsigned)(wkeys[n] & 0xFFFFFFFFull);
    id &= (VSZ - 1);   // safety clamp
    atomicAdd(&counts[id], 1);
    int b = n >> 13, p = n & (PLANE - 1);
    const float4* row = (const float4*)(emb + id * CDIM);
    float* dst = fh + b * BSTR + p;
#pragma unroll
    for (int r = 0; r < 8; ++r) {
        float4 v = row[r];
        dst[(r * 4 + 0) * PLANE] = v.x;
        dst[(r * 4 + 1) * PLANE] = v.y;
        dst[(r * 4 + 2) * PLANE] = v.z;
        dst[(r * 4 + 3) * PLANE] = v.w;
    }
}

// ---------------- K_conv: fused conv3x3x3 + blend + fhat store + loss ----------------
__global__ __launch_bounds__(256) void k_conv(const float* __restrict__ fh,
                                              const float* __restrict__ cw,
                                              const float* __restrict__ bias,
                                              const float* __restrict__ f,
                                              float* __restrict__ out,
                                              float* __restrict__ loss_sum) {
    const int tid = threadIdx.x;
    const int n = (blockIdx.x & 63) * 256 + tid;   // 0..16383
    const int cog = blockIdx.x >> 6;               // 0..7
    const int b = n >> 13, p = n & (PLANE - 1);
    const int t = p >> 10, h = (p >> 5) & 31, wi = p & 31;

    float msk[27];
#pragma unroll
    for (int dt = 0; dt < 3; ++dt)
#pragma unroll
        for (int dh = 0; dh < 3; ++dh)
#pragma unroll
            for (int dw = 0; dw < 3; ++dw) {
                bool ok = ((unsigned)(t + dt - 1) < 8u) &&
                          ((unsigned)(h + dh - 1) < 32u) &&
                          ((unsigned)(wi + dw - 1) < 32u);
                msk[dt * 9 + dh * 3 + dw] = ok ? 1.0f : 0.0f;
            }

    const float* xb = fh + b * BSTR + p;
    const float* wp = cw + cog * 4 * 864;
    float acc[4] = {0.f, 0.f, 0.f, 0.f};

    for (int ci = 0; ci < CDIM; ++ci) {
        const float* xr = xb + ci * PLANE;
        const float* x0 = xr - 1024;
        const float* x1 = xr;
        const float* x2 = xr + 1024;
#pragma unroll
        for (int dt = 0; dt < 3; ++dt) {
            const float* xp = (dt == 0) ? x0 : ((dt == 1) ? x1 : x2);
#pragma unroll
            for (int dh = 0; dh < 3; ++dh) {
#pragma unroll
                for (int dw = 0; dw < 3; ++dw) {
                    int u = dt * 9 + dh * 3 + dw;
                    float x = xp[(dh - 1) * 32 + (dw - 1)] * msk[u];
#pragma unroll
                    for (int k = 0; k < 4; ++k)
                        acc[k] = fmaf(wp[k * 864 + ci * 27 + u], x, acc[k]);
                }
            }
        }
    }

    float s = 0.f;
#pragma unroll
    for (int k = 0; k < 4; ++k) {
        int co = cog * 4 + k;
        long off = (long)b * BSTR + (long)co * PLANE + p;
        float fhc = fh[off];
        float fv = f[off];
        float o = 0.5f * fhc + 0.5f * (acc[k] + bias[co]);
        out[off] = o;
        float d = o - fv;
        s = fmaf(d, d, s);
    }
#pragma unroll
    for (int off = 32; off > 0; off >>= 1) s += __shfl_down(s, off, 64);
    __shared__ float ls[4];
    if ((tid & 63) == 0) ls[tid >> 6] = s;
    __syncthreads();
    if (tid == 0) atomicAdd(loss_sum, ls[0] + ls[1] + ls[2] + ls[3]);
}

// ---------------- K_scalars ----------------
__global__ void k_scalars(const int* __restrict__ counts,
                          const float* __restrict__ loss_sum, float* __restrict__ out) {
    int tid = threadIdx.x;
    int used = 0;
#pragma unroll
    for (int r = 0; r < 32; ++r) used += (counts[tid + 256 * r] > 0) ? 1 : 0;
#pragma unroll
    for (int off = 32; off > 0; off >>= 1) used += __shfl_down(used, off, 64);
    __shared__ int us[4];
    if ((tid & 63) == 0) us[tid >> 6] = used;
    __syncthreads();
    if (tid == 0) {
        int u = us[0] + us[1] + us[2] + us[3];
        out[NEL + 0] = 1.25f * (*loss_sum) / (float)NEL;
        out[NEL + 1] = ((float)u / (float)VSZ) * 100.0f;
    }
}

extern "C" void kernel_launch(void* const* d_in, const int* in_sizes, int n_in,
                              void* d_out, int out_size, void* d_ws, size_t ws_size,
                              hipStream_t stream) {
    const float* f      = (const float*)d_in[0];
    const float* emb    = (const float*)d_in[1];
    const float* conv_w = (const float*)d_in[2];
    const float* conv_b = (const float*)d_in[3];
    float* out = (float*)d_out;
    float* ws = (float*)d_ws;

    // ws layout (float offsets) — stays within the round-6 proven ~2.37 MB envelope.
    float*    enorm    = ws;                        // [0, 8192)
    u64*      wkeys    = (u64*)(ws + 8192);         // [8192, 40960)  u64 x 16384
    int*      counts   = (int*)(ws + 40960);        // [40960, 49152)
    float*    loss_sum = ws + 49152;                // 1
    int*      rq_cnt   = (int*)(ws + 49156);        // 1
    unsigned* rq       = (unsigned*)(ws + 49408);   // up to 16384 flagged queries
    float*    fh       = ws + 67648;                // 524288 floats (2 MB) + margin
    // Overlays (dead before their consumers):
    //   part_best (u64 x 16 x 16384 = 2 MB) on fh  — consumed by k_reduce BEFORE k_gather
    u64*      part_best = (u64*)fh;
    //   part_sec (u32 x 16 x 16384 = 1 MB) on d_out — consumed by k_reduce BEFORE k_conv
    unsigned* part_sec  = (unsigned*)out;

    k_pre<<<64, 256, 0, stream>>>(emb, enorm, counts, loss_sum, rq_cnt);
    k_minidx<<<1024, 256, 0, stream>>>(f, emb, enorm, part_best, part_sec);
    k_reduce<<<64, 256, 0, stream>>>(part_best, part_sec, wkeys, rq, rq_cnt);
    k_rescan<<<256, 256, 0, stream>>>(rq, rq_cnt, f, emb, enorm, wkeys);
    k_gather<<<64, 256, 0, stream>>>(wkeys, emb, fh, counts);
    k_conv<<<512, 256, 0, stream>>>(fh, conv_w, conv_b, f, out, loss_sum);
    k_scalars<<<1, 256, 0, stream>>>(counts, loss_sum, out);
}